// Round 5
// baseline (614.633 us; speedup 1.0000x reference)
//
#include <hip/hip_runtime.h>
#include <cstdint>
#include <cstddef>

// Problem constants (B=2, S=4096 -> T=8192 tokens)
#define T_TOK 8192
#define DIM   1024   // D
#define NE    8      // experts
#define FF    2048   // F
#define TOPK  2

typedef __bf16 bf16x8 __attribute__((ext_vector_type(8)));
typedef float  floatx4 __attribute__((ext_vector_type(4)));

__device__ __forceinline__ unsigned short f2bf(float f) {
  unsigned int u = __float_as_uint(f);
  unsigned int r = 0x7FFFu + ((u >> 16) & 1u);   // round-to-nearest-even
  return (unsigned short)((u + r) >> 16);
}

__device__ __forceinline__ void gl_lds16(const void* g, void* l) {
  __builtin_amdgcn_global_load_lds(
      (__attribute__((address_space(1))) void*)g,
      (__attribute__((address_space(3))) void*)l,
      16, 0, 0);
}

// ---------------------------------------------------------------------------
// Transpose + f32->bf16 convert:  in[e][r][c] (f32) -> out[e][c][r] (bf16)
// ---------------------------------------------------------------------------
__global__ __launch_bounds__(256) void transpose_bf16_kernel(
    const float* __restrict__ in, unsigned short* __restrict__ out,
    int R, int C)
{
  __shared__ float tile[32][33];
  int e  = blockIdx.z;
  int c0 = blockIdx.x * 32, r0 = blockIdx.y * 32;
  int tx = threadIdx.x & 31, ty = threadIdx.x >> 5;   // 32 x 8
  const float* inp = in + (size_t)e * R * C;
  unsigned short* op = out + (size_t)e * R * C;
  for (int i = 0; i < 4; ++i)
    tile[ty + i * 8][tx] = inp[(size_t)(r0 + ty + i * 8) * C + c0 + tx];
  __syncthreads();
  for (int i = 0; i < 4; ++i)
    op[(size_t)(c0 + ty + i * 8) * R + r0 + tx] = f2bf(tile[tx][ty + i * 8]);
}

// ---------------------------------------------------------------------------
// Gating pass 1: one wave per token (4 waves/block). gw staged TRANSPOSED in
// LDS. f64 logit accumulation (top-2 robust vs np ref). Fused x->bf16.
// ---------------------------------------------------------------------------
__global__ __launch_bounds__(256) void gate_kernel(
    const float* __restrict__ x, const float* __restrict__ gw,
    unsigned short* __restrict__ xb, int* __restrict__ tokExp,
    float* __restrict__ tokW)
{
  __shared__ float gwT[NE][DIM];   // 32 KB
  int tid = threadIdx.x;
  for (int i = tid; i < DIM * NE; i += 256) {
    int d = i >> 3, e = i & 7;
    gwT[e][d] = gw[i];
  }
  __syncthreads();

  int wv = tid >> 6, lane = tid & 63;
  int t = blockIdx.x * 4 + wv;
  const float* xrow = x + (size_t)t * DIM;
  unsigned short* xbrow = xb + (size_t)t * DIM;

  double acc[NE];
  for (int e = 0; e < NE; ++e) acc[e] = 0.0;

  for (int j = 0; j < 4; ++j) {
    float4 xv = ((const float4*)xrow)[j * 64 + lane];
    ushort4 s;
    s.x = f2bf(xv.x); s.y = f2bf(xv.y); s.z = f2bf(xv.z); s.w = f2bf(xv.w);
    ((ushort4*)xbrow)[j * 64 + lane] = s;
    double xd0 = (double)xv.x, xd1 = (double)xv.y;
    double xd2 = (double)xv.z, xd3 = (double)xv.w;
    for (int e = 0; e < NE; ++e) {
      float4 g = ((const float4*)&gwT[e][0])[j * 64 + lane];
      acc[e] += xd0 * (double)g.x + xd1 * (double)g.y +
                xd2 * (double)g.z + xd3 * (double)g.w;
    }
  }

  for (int s = 32; s > 0; s >>= 1)
    for (int e = 0; e < NE; ++e)
      acc[e] += __shfl_down(acc[e], s, 64);

  if (lane == 0) {
    int e0 = 0; double v0 = acc[0];
    for (int e = 1; e < NE; ++e) if (acc[e] > v0) { v0 = acc[e]; e0 = e; }
    int e1 = -1; double v1 = -1.0e300;
    for (int e = 0; e < NE; ++e) {
      if (e == e0) continue;
      if (acc[e] > v1) { v1 = acc[e]; e1 = e; }
    }
    float a = (float)v0, b = (float)v1;
    float eb = __expf(b - a);
    float den = 1.0f + eb;
    tokExp[t] = e0 | (e1 << 8);
    tokW[2 * t + 0] = 1.0f / den;
    tokW[2 * t + 1] = eb / den;
  }
}

// ---------------------------------------------------------------------------
// Gating pass 2: slot assignment with ZERO atomics (ballot+popcount prefix).
// ---------------------------------------------------------------------------
__global__ __launch_bounds__(64) void assign_kernel(
    const int* __restrict__ tokExp, int* __restrict__ tokEnc,
    int* __restrict__ tIdx, int* __restrict__ cnt, int* __restrict__ off)
{
  int lane = threadIdx.x;
  unsigned long long below = (1ull << lane) - 1ull;
  int base[NE];
  for (int e = 0; e < NE; ++e) base[e] = 0;

  for (int it = 0; it < T_TOK / 64; ++it) {
    int t = it * 64 + lane;
    int enc = tokExp[t];
    int e0 = enc & 0xFF, e1 = (enc >> 8) & 0xFF;
    int s0 = 0, s1 = 0;
    for (int e = 0; e < NE; ++e) {
      unsigned long long m0 = __ballot(e0 == e);
      unsigned long long m1 = __ballot(e1 == e);
      if (e0 == e) s0 = base[e] + __popcll(m0 & below);
      if (e1 == e) s1 = base[e] + __popcll(m0) + __popcll(m1 & below);
      base[e] += __popcll(m0) + __popcll(m1);
    }
    tokEnc[2 * t + 0] = (e0 << 16) | s0;
    tokEnc[2 * t + 1] = (e1 << 16) | s1;
    tIdx[e0 * T_TOK + s0] = t;
    tIdx[e1 * T_TOK + s1] = t;
  }

  if (lane == 0) {
    int a = 0;
    for (int e = 0; e < NE; ++e) { cnt[e] = base[e]; off[e] = a; a += base[e]; }
    off[NE] = a;
  }
}

// ---------------------------------------------------------------------------
// Pipelined GEMM core: 128x128 tile, stage=BK32, 3 LDS buffers, depth-2
// prefetch via global_load_lds. Raw s_barrier + fine vmcnt: prefetch for
// stages s+1/s+2 is NEVER drained (unlike __syncthreads' vmcnt(0)).
// Per stage per wave: 4 gl_lds16 (issue s+2) + 8 ds_read_b128 + 16 MFMA.
// Invariant at stage top: 8 loads outstanding (4 for s, 4 for s+1);
// wait vmcnt(4) completes stage-s loads. lgkmcnt(0) closes the
// DMA-write-vs-inflight-ds_read race on buffer reuse ((s+2)%3==(s-1)%3).
// ---------------------------------------------------------------------------
#define GEMM_PIPE(NSTAGES)                                                    \
  {                                                                           \
    issue(0, 0); issue(1, 1);                                                 \
    int cb = 0, ib = 2;                                                       \
    for (int s = 0; s < (NSTAGES); ++s) {                                     \
      if (s + 1 < (NSTAGES))                                                  \
        asm volatile("s_waitcnt vmcnt(4) lgkmcnt(0)\ns_barrier" ::: "memory");\
      else                                                                    \
        asm volatile("s_waitcnt vmcnt(0) lgkmcnt(0)\ns_barrier" ::: "memory");\
      if (s + 2 < (NSTAGES)) issue(s + 2, ib);                                \
      bf16x8 af[4], bf[4];                                                    \
      for (int mi = 0; mi < 4; ++mi)                                          \
        af[mi] = *(const bf16x8*)&As[cb][quad][wr * 64 + mi * 16 + li][0];    \
      for (int ni = 0; ni < 4; ++ni)                                          \
        bf[ni] = *(const bf16x8*)&Bs[cb][quad][wc * 64 + ni * 16 + li][0];    \
      for (int mi = 0; mi < 4; ++mi)                                          \
        for (int ni = 0; ni < 4; ++ni)                                        \
          acc[mi][ni] = __builtin_amdgcn_mfma_f32_16x16x32_bf16(              \
              af[mi], bf[ni], acc[mi][ni], 0, 0, 0);                          \
      if (++cb == 3) cb = 0;                                                  \
      if (++ib == 3) ib = 0;                                                  \
    }                                                                         \
  }

// ---------------------------------------------------------------------------
// GEMM1: h[row][f] = silu( sum_d xb[tok(row)][d] * w1t[e][f][d] )   (bf16 out)
// XCD-pinned 1-D launch (g&7 = XCD = expert).
// ---------------------------------------------------------------------------
__global__ __launch_bounds__(256, 4) void gemm1_kernel(
    const unsigned short* __restrict__ xb,   // [T][D] bf16
    const unsigned short* __restrict__ w1t,  // [E][F][D] bf16
    unsigned short* __restrict__ h,          // [2T][F] bf16 (compacted)
    const int* __restrict__ tIdx, const int* __restrict__ cnt,
    const int* __restrict__ off)
{
  // decode swizzled 1-D id: g = (phase*512 + m*8 + nl)*8 + e
  int g = blockIdx.x;
  int e = g & 7;
  int b = g >> 3;              // 0..1023
  int phase = b >> 9;          // 0..1  (n-half)
  int m = (b >> 3) & 63;       // 0..63 (M-tile)
  int nl = b & 7;              // 0..7  (n within half)
  int count = cnt[e];
  int r0 = m * 128;
  if (r0 >= count) return;
  int n0 = (phase * 8 + nl) * 128;

  __shared__ __align__(16) unsigned short As[3][4][128][8];   // 24 KB
  __shared__ __align__(16) unsigned short Bs[3][4][128][8];   // 24 KB

  int tid = threadIdx.x, lane = tid & 63, w = tid >> 6;
  int wr = w >> 1, wc = w & 1;
  int quad = lane >> 4, li = lane & 15;

  const unsigned short* ag[2];
  const unsigned short* bg[2];
  for (int c = 0; c < 2; ++c) {
    int mm = c * 64 + lane;
    int r = r0 + mm; if (r > count - 1) r = count - 1;
    ag[c] = xb + (size_t)tIdx[e * T_TOK + r] * DIM;
    bg[c] = w1t + ((size_t)e * FF + (n0 + mm)) * DIM;
  }

  auto issue = [&](int s, int buf) {
    int koff = s * 32 + w * 8;
    gl_lds16(ag[0] + koff, &As[buf][w][0][0]);
    gl_lds16(ag[1] + koff, &As[buf][w][64][0]);
    gl_lds16(bg[0] + koff, &Bs[buf][w][0][0]);
    gl_lds16(bg[1] + koff, &Bs[buf][w][64][0]);
  };

  floatx4 acc[4][4];
  for (int mi = 0; mi < 4; ++mi)
    for (int ni = 0; ni < 4; ++ni)
      for (int q = 0; q < 4; ++q) acc[mi][ni][q] = 0.0f;

  GEMM_PIPE(DIM / 32)

  size_t hb = (size_t)off[e];
  for (int mi = 0; mi < 4; ++mi) {
    int rowb = wr * 64 + mi * 16 + quad * 4;
    for (int rr = 0; rr < 4; ++rr) {
      int r = r0 + rowb + rr;
      if (r >= count) continue;
      unsigned short* hrow = h + (hb + r) * FF + n0 + wc * 64 + li;
      for (int ni = 0; ni < 4; ++ni) {
        float v = acc[mi][ni][rr];
        float s = v / (1.0f + __expf(-v));   // silu
        hrow[ni * 16] = f2bf(s);
      }
    }
  }
}

// ---------------------------------------------------------------------------
// GEMM2: yv[row][d] = sum_f h[row][f] * w2t[e][d][f]    (f32 out)
// ---------------------------------------------------------------------------
__global__ __launch_bounds__(256, 4) void gemm2_kernel(
    const unsigned short* __restrict__ h,    // [2T][F] bf16
    const unsigned short* __restrict__ w2t,  // [E][D][F] bf16
    float* __restrict__ yv,                  // [2T][D] f32
    const int* __restrict__ cnt, const int* __restrict__ off)
{
  // decode swizzled 1-D id: g = (phase*256 + m*4 + nl)*8 + e
  int g = blockIdx.x;
  int e = g & 7;
  int b = g >> 3;              // 0..511
  int phase = b >> 8;          // 0..1
  int m = (b >> 2) & 63;       // 0..63
  int nl = b & 3;              // 0..3
  int count = cnt[e];
  int r0 = m * 128;
  if (r0 >= count) return;
  int n0 = (phase * 4 + nl) * 128;

  __shared__ __align__(16) unsigned short As[3][4][128][8];   // 24 KB
  __shared__ __align__(16) unsigned short Bs[3][4][128][8];   // 24 KB

  int tid = threadIdx.x, lane = tid & 63, w = tid >> 6;
  int wr = w >> 1, wc = w & 1;
  int quad = lane >> 4, li = lane & 15;
  size_t yb = (size_t)off[e];

  const unsigned short* ag[2];
  const unsigned short* bg[2];
  for (int c = 0; c < 2; ++c) {
    int mm = c * 64 + lane;
    int r = r0 + mm; if (r > count - 1) r = count - 1;
    ag[c] = h + (yb + r) * FF;
    bg[c] = w2t + ((size_t)e * DIM + (n0 + mm)) * FF;
  }

  auto issue = [&](int s, int buf) {
    int koff = s * 32 + w * 8;
    gl_lds16(ag[0] + koff, &As[buf][w][0][0]);
    gl_lds16(ag[1] + koff, &As[buf][w][64][0]);
    gl_lds16(bg[0] + koff, &Bs[buf][w][0][0]);
    gl_lds16(bg[1] + koff, &Bs[buf][w][64][0]);
  };

  floatx4 acc[4][4];
  for (int mi = 0; mi < 4; ++mi)
    for (int ni = 0; ni < 4; ++ni)
      for (int q = 0; q < 4; ++q) acc[mi][ni][q] = 0.0f;

  GEMM_PIPE(FF / 32)

  for (int mi = 0; mi < 4; ++mi) {
    int rowb = wr * 64 + mi * 16 + quad * 4;
    for (int rr = 0; rr < 4; ++rr) {
      int r = r0 + rowb + rr;
      if (r >= count) continue;
      float* yrow = yv + (yb + r) * DIM + n0 + wc * 64 + li;
      for (int ni = 0; ni < 4; ++ni)
        yrow[ni * 16] = acc[mi][ni][rr];
    }
  }
}

// ---------------------------------------------------------------------------
// Combine: out[t] = w0 * yv[row0] + w1 * yv[row1]
// ---------------------------------------------------------------------------
__global__ __launch_bounds__(256) void combine_kernel(
    const float* __restrict__ yv, const int* __restrict__ tokEnc,
    const float* __restrict__ tokW, const int* __restrict__ off,
    float* __restrict__ out)
{
  int t = blockIdx.x;
  int i = threadIdx.x;   // 256 threads x float4 = 1024 = D
  int enc0 = tokEnc[2 * t + 0], enc1 = tokEnc[2 * t + 1];
  float w0 = tokW[2 * t + 0], w1 = tokW[2 * t + 1];
  size_t row0 = (size_t)off[enc0 >> 16] + (enc0 & 0xFFFF);
  size_t row1 = (size_t)off[enc1 >> 16] + (enc1 & 0xFFFF);
  float4 a = ((const float4*)(yv + row0 * DIM))[i];
  float4 b = ((const float4*)(yv + row1 * DIM))[i];
  float4 o;
  o.x = w0 * a.x + w1 * b.x;
  o.y = w0 * a.y + w1 * b.y;
  o.z = w0 * a.z + w1 * b.z;
  o.w = w0 * a.w + w1 * b.w;
  ((float4*)(out + (size_t)t * DIM))[i] = o;
}

// ---------------------------------------------------------------------------
extern "C" void kernel_launch(void* const* d_in, const int* in_sizes, int n_in,
                              void* d_out, int out_size, void* d_ws, size_t ws_size,
                              hipStream_t stream)
{
  const float* x  = (const float*)d_in[0];   // [T][D]
  const float* gw = (const float*)d_in[1];   // [D][E]
  const float* w1 = (const float*)d_in[2];   // [E][D][F]
  const float* w2 = (const float*)d_in[3];   // [E][F][D]
  float* out = (float*)d_out;                // [T][D]

  // workspace carve-up (256B aligned)
  size_t o = 0;
  auto alloc = [&](size_t bytes) {
    void* p = (char*)d_ws + o;
    o += (bytes + 255) & ~(size_t)255;
    return p;
  };
  unsigned short* xb   = (unsigned short*)alloc((size_t)T_TOK * DIM * 2);      // 16.8 MB
  unsigned short* w1t  = (unsigned short*)alloc((size_t)NE * DIM * FF * 2);    // 33.6 MB
  unsigned short* w2t  = (unsigned short*)alloc((size_t)NE * DIM * FF * 2);    // 33.6 MB
  unsigned short* hbuf = (unsigned short*)alloc((size_t)T_TOK * TOPK * FF * 2);// 67.1 MB
  float*          yv   = (float*)alloc((size_t)T_TOK * TOPK * DIM * 4);        // 67.1 MB
  int*   tIdx   = (int*)alloc((size_t)NE * T_TOK * 4);
  int*   tokEnc = (int*)alloc((size_t)2 * T_TOK * 4);
  float* tokW   = (float*)alloc((size_t)2 * T_TOK * 4);
  int*   tokExp = (int*)alloc((size_t)T_TOK * 4);
  int*   cnt    = (int*)alloc((size_t)NE * 4);
  int*   off    = (int*)alloc((size_t)(NE + 1) * 4);

  // w1 [E][D][F] -> w1t [E][F][D] ; w2 [E][F][D] -> w2t [E][D][F]
  transpose_bf16_kernel<<<dim3(FF / 32, DIM / 32, NE), 256, 0, stream>>>(w1, w1t, DIM, FF);
  transpose_bf16_kernel<<<dim3(DIM / 32, FF / 32, NE), 256, 0, stream>>>(w2, w2t, FF, DIM);

  gate_kernel<<<T_TOK / 4, 256, 0, stream>>>(x, gw, xb, tokExp, tokW);
  assign_kernel<<<1, 64, 0, stream>>>(tokExp, tokEnc, tIdx, cnt, off);

  // XCD-pinned swizzled 1-D grids (g & 7 = XCD = expert)
  gemm1_kernel<<<8192, 256, 0, stream>>>(xb, w1t, hbuf, tIdx, cnt, off);
  gemm2_kernel<<<4096, 256, 0, stream>>>(hbuf, w2t, yv, cnt, off);
  combine_kernel<<<T_TOK, 256, 0, stream>>>(yv, tokEnc, tokW, off, out);
}